// Round 17
// baseline (433.207 us; speedup 1.0000x reference)
//
#include <hip/hip_runtime.h>
#include <hip/hip_bf16.h>
#include <math.h>

#define QLEN 1024
#define MLEN 1024
#define BSZ 4
#define KLEN 2048
#define NH 16
#define DH 64
#define DM 1024
#define DI 4096
#define NHD 1024
#define LN_EPS 1e-5f

typedef short bf16x8 __attribute__((ext_vector_type(8)));
typedef float f32x4 __attribute__((ext_vector_type(4)));
typedef unsigned int uint4v __attribute__((ext_vector_type(4)));

__device__ __forceinline__ float bf2f(unsigned short u) {
    union { unsigned u32; float f; } x; x.u32 = ((unsigned)u) << 16; return x.f;
}
__device__ __forceinline__ unsigned short f2bf(float f) {
    __hip_bfloat16 h = __float2bfloat16(f);
    return *(unsigned short*)&h;
}

// ---------------- workspace layout (BYTE offsets) ----------------
static const size_t OFF_CATB  = 0;
static const size_t OFF_VTG   = 0;
static const size_t OFF_WHB   = 16777216;
static const size_t OFF_RB    = 67108864;
static const size_t OFF_RHKB  = 71303168;
static const size_t OFF_AVB   = 75497472;
static const size_t OFF_TMPB  = 83886080;
static const size_t OFF_ML    = 92274688;
static const size_t OFF_LN1F  = 100663296;
static const size_t OFF_LN1B  = 117440512;
static const size_t OFF_FFHB  = 125829120;
static const size_t OFF_QKVWT = 159383552;
static const size_t OFF_RWT   = 165675008;
static const size_t OFF_OWT   = 167772160;
static const size_t OFF_FFW1T = 169869312;
static const size_t OFF_FFW2T = 178257920;

// ---------------- casts ----------------
__global__ __launch_bounds__(256) void cast_cat(const float* __restrict__ mems,
                                                const float* __restrict__ dec,
                                                unsigned short* __restrict__ out) {
    size_t i8 = ((size_t)blockIdx.x * 256 + threadIdx.x) * 8;
    const size_t half = (size_t)MLEN * BSZ * DM;
    const float* src = (i8 < half) ? (mems + i8) : (dec + (i8 - half));
    float4 v0 = *(const float4*)src;
    float4 v1 = *(const float4*)(src + 4);
    ushort4 o0 = {f2bf(v0.x), f2bf(v0.y), f2bf(v0.z), f2bf(v0.w)};
    ushort4 o1 = {f2bf(v1.x), f2bf(v1.y), f2bf(v1.z), f2bf(v1.w)};
    *(ushort4*)&out[i8] = o0;
    *(ushort4*)&out[i8 + 4] = o1;
}

__global__ __launch_bounds__(256) void cast_f32_bf16(const float* __restrict__ in,
                                                     unsigned short* __restrict__ out) {
    size_t i8 = ((size_t)blockIdx.x * 256 + threadIdx.x) * 8;
    float4 v0 = *(const float4*)(in + i8);
    float4 v1 = *(const float4*)(in + i8 + 4);
    ushort4 o0 = {f2bf(v0.x), f2bf(v0.y), f2bf(v0.z), f2bf(v0.w)};
    ushort4 o1 = {f2bf(v1.x), f2bf(v1.y), f2bf(v1.z), f2bf(v1.w)};
    *(ushort4*)&out[i8] = o0;
    *(ushort4*)&out[i8 + 4] = o1;
}

// all 5 weight transposes fused: [K][N] fp32 -> [N][K] bf16
__global__ __launch_bounds__(256) void transpose_cast_all(
        const float* __restrict__ qkv_w, const float* __restrict__ r_w,
        const float* __restrict__ o_w,  const float* __restrict__ ff_w1,
        const float* __restrict__ ff_w2,
        unsigned short* __restrict__ qkvwT, unsigned short* __restrict__ rwT,
        unsigned short* __restrict__ owT, unsigned short* __restrict__ ffw1T,
        unsigned short* __restrict__ ffw2T) {
    __shared__ float tile[32][33];
    const int bid = blockIdx.x;
    const float* in; unsigned short* out; int K, N, nx, lid;
    if (bid < 3072)      { in = qkv_w; out = qkvwT; K = 1024; N = 3072; nx = 96;  lid = bid; }
    else if (bid < 4096) { in = r_w;   out = rwT;   K = 1024; N = 1024; nx = 32;  lid = bid - 3072; }
    else if (bid < 5120) { in = o_w;   out = owT;   K = 1024; N = 1024; nx = 32;  lid = bid - 4096; }
    else if (bid < 9216) { in = ff_w1; out = ffw1T; K = 1024; N = 4096; nx = 128; lid = bid - 5120; }
    else                 { in = ff_w2; out = ffw2T; K = 4096; N = 1024; nx = 32;  lid = bid - 9216; }
    const int n0 = (lid % nx) * 32;
    const int k0 = (lid / nx) * 32;
    const int t = threadIdx.x;
    const int r = t >> 3;
    const int c0 = (t & 7) << 2;
    float4 v = *(const float4*)&in[(size_t)(k0 + r) * N + n0 + c0];
    tile[r][c0 + 0] = v.x; tile[r][c0 + 1] = v.y;
    tile[r][c0 + 2] = v.z; tile[r][c0 + 3] = v.w;
    __syncthreads();
    ushort4 o = {f2bf(tile[c0 + 0][r]), f2bf(tile[c0 + 1][r]),
                 f2bf(tile[c0 + 2][r]), f2bf(tile[c0 + 3][r])};
    *(ushort4*)&out[(size_t)(n0 + r) * K + k0 + c0] = o;
}

// ---------------- bf16 MFMA GEMM 128x128 (proven: reg-staged dbuf + XOR swizzle) ------
__global__ __launch_bounds__(256) void gemm_bf16(const unsigned short* __restrict__ A,
                                                 const unsigned short* __restrict__ Bt,
                                                 const float* __restrict__ bias,
                                                 void* __restrict__ C,
                                                 int M, int N, int K, int flags) {
    __shared__ __align__(16) unsigned short As[128 * 64];
    __shared__ __align__(16) unsigned short Bs[128 * 64];

    const int tid = threadIdx.x;
    const int w = tid >> 6, l = tid & 63;
    const int wr = w >> 1, wc = w & 1;
    const int row0 = blockIdx.y * 128;
    const int col0 = blockIdx.x * 128;

    f32x4 acc[4][4] = {};

    uint4v ra[4], rb[4];
    {
#pragma unroll
        for (int q = 0; q < 4; ++q) {
            int f = q * 256 + tid, r = f >> 3, c = f & 7;
            ra[q] = *(const uint4v*)&A[(size_t)(row0 + r) * K + c * 8];
            rb[q] = *(const uint4v*)&Bt[(size_t)(col0 + r) * K + c * 8];
        }
    }

    const int nt = K >> 6;
    for (int kt = 0; kt < nt; ++kt) {
        __syncthreads();
#pragma unroll
        for (int q = 0; q < 4; ++q) {
            int f = q * 256 + tid, r = f >> 3, c = f & 7;
            int sw = (c ^ (r & 7)) << 3;
            *(uint4v*)&As[r * 64 + sw] = ra[q];
            *(uint4v*)&Bs[r * 64 + sw] = rb[q];
        }
        __syncthreads();
        if (kt + 1 < nt) {
            const int k0 = (kt + 1) << 6;
#pragma unroll
            for (int q = 0; q < 4; ++q) {
                int f = q * 256 + tid, r = f >> 3, c = f & 7;
                ra[q] = *(const uint4v*)&A[(size_t)(row0 + r) * K + k0 + c * 8];
                rb[q] = *(const uint4v*)&Bt[(size_t)(col0 + r) * K + k0 + c * 8];
            }
        }
#pragma unroll
        for (int ks = 0; ks < 2; ++ks) {
            bf16x8 a[4], bfr[4];
#pragma unroll
            for (int m = 0; m < 4; ++m) {
                int arow = wr * 64 + m * 16 + (l & 15);
                int chunk = (ks * 4 + (l >> 4)) ^ (arow & 7);
                a[m] = *(const bf16x8*)&As[arow * 64 + chunk * 8];
            }
#pragma unroll
            for (int n = 0; n < 4; ++n) {
                int brow = wc * 64 + n * 16 + (l & 15);
                int chunk = (ks * 4 + (l >> 4)) ^ (brow & 7);
                bfr[n] = *(const bf16x8*)&Bs[brow * 64 + chunk * 8];
            }
#pragma unroll
            for (int m = 0; m < 4; ++m)
#pragma unroll
                for (int n = 0; n < 4; ++n)
                    acc[m][n] = __builtin_amdgcn_mfma_f32_16x16x32_bf16(a[m], bfr[n], acc[m][n], 0, 0, 0);
        }
    }

#pragma unroll
    for (int n = 0; n < 4; ++n) {
        const int ccol = col0 + wc * 64 + n * 16 + (l & 15);
        const float bv = (flags & 1) ? bias[ccol] : 0.0f;
#pragma unroll
        for (int m = 0; m < 4; ++m) {
            const int crow0 = row0 + wr * 64 + m * 16 + ((l >> 4) << 2);
#pragma unroll
            for (int reg = 0; reg < 4; ++reg) {
                float v = acc[m][n][reg] + bv;
                if (flags & 2) v = fmaxf(v, 0.0f);
                if (flags & 4)
                    ((unsigned short*)C)[(size_t)(crow0 + reg) * N + ccol] = f2bf(v);
                else
                    ((float*)C)[(size_t)(crow0 + reg) * N + ccol] = v;
            }
        }
    }
}

// ---------------- bf16 MFMA GEMM 256x128 wide (8 waves, same inner structure) ---------
__global__ __launch_bounds__(512, 4) void gemm_bf16_wide(const unsigned short* __restrict__ A,
                                                         const unsigned short* __restrict__ Bt,
                                                         const float* __restrict__ bias,
                                                         void* __restrict__ C,
                                                         int M, int N, int K, int flags) {
    __shared__ __align__(16) unsigned short As[256 * 64];   // 32 KB
    __shared__ __align__(16) unsigned short Bs[128 * 64];   // 16 KB

    const int tid = threadIdx.x;
    const int w = tid >> 6, l = tid & 63;
    const int wr = w >> 1, wc = w & 1;          // wr 0..3, wc 0..1
    const int row0 = blockIdx.y * 256;
    const int col0 = blockIdx.x * 128;

    f32x4 acc[4][4] = {};

    uint4v ra[4], rb[2];
    {
#pragma unroll
        for (int q = 0; q < 4; ++q) {
            int f = q * 512 + tid, r = f >> 3, c = f & 7;
            ra[q] = *(const uint4v*)&A[(size_t)(row0 + r) * K + c * 8];
        }
#pragma unroll
        for (int q = 0; q < 2; ++q) {
            int f = q * 512 + tid, r = f >> 3, c = f & 7;
            rb[q] = *(const uint4v*)&Bt[(size_t)(col0 + r) * K + c * 8];
        }
    }

    const int nt = K >> 6;
    for (int kt = 0; kt < nt; ++kt) {
        __syncthreads();
#pragma unroll
        for (int q = 0; q < 4; ++q) {
            int f = q * 512 + tid, r = f >> 3, c = f & 7;
            *(uint4v*)&As[r * 64 + ((c ^ (r & 7)) << 3)] = ra[q];
        }
#pragma unroll
        for (int q = 0; q < 2; ++q) {
            int f = q * 512 + tid, r = f >> 3, c = f & 7;
            *(uint4v*)&Bs[r * 64 + ((c ^ (r & 7)) << 3)] = rb[q];
        }
        __syncthreads();
        if (kt + 1 < nt) {
            const int k0 = (kt + 1) << 6;
#pragma unroll
            for (int q = 0; q < 4; ++q) {
                int f = q * 512 + tid, r = f >> 3, c = f & 7;
                ra[q] = *(const uint4v*)&A[(size_t)(row0 + r) * K + k0 + c * 8];
            }
#pragma unroll
            for (int q = 0; q < 2; ++q) {
                int f = q * 512 + tid, r = f >> 3, c = f & 7;
                rb[q] = *(const uint4v*)&Bt[(size_t)(col0 + r) * K + k0 + c * 8];
            }
        }
#pragma unroll
        for (int ks = 0; ks < 2; ++ks) {
            bf16x8 a[4], bfr[4];
#pragma unroll
            for (int m = 0; m < 4; ++m) {
                int arow = wr * 64 + m * 16 + (l & 15);
                int chunk = (ks * 4 + (l >> 4)) ^ (arow & 7);
                a[m] = *(const bf16x8*)&As[arow * 64 + chunk * 8];
            }
#pragma unroll
            for (int n = 0; n < 4; ++n) {
                int brow = wc * 64 + n * 16 + (l & 15);
                int chunk = (ks * 4 + (l >> 4)) ^ (brow & 7);
                bfr[n] = *(const bf16x8*)&Bs[brow * 64 + chunk * 8];
            }
#pragma unroll
            for (int m = 0; m < 4; ++m)
#pragma unroll
                for (int n = 0; n < 4; ++n)
                    acc[m][n] = __builtin_amdgcn_mfma_f32_16x16x32_bf16(a[m], bfr[n], acc[m][n], 0, 0, 0);
        }
    }

#pragma unroll
    for (int n = 0; n < 4; ++n) {
        const int ccol = col0 + wc * 64 + n * 16 + (l & 15);
        const float bv = (flags & 1) ? bias[ccol] : 0.0f;
#pragma unroll
        for (int m = 0; m < 4; ++m) {
            const int crow0 = row0 + wr * 64 + m * 16 + ((l >> 4) << 2);
#pragma unroll
            for (int reg = 0; reg < 4; ++reg) {
                float v = acc[m][n][reg] + bv;
                if (flags & 2) v = fmaxf(v, 0.0f);
                if (flags & 4)
                    ((unsigned short*)C)[(size_t)(crow0 + reg) * N + ccol] = f2bf(v);
                else
                    ((float*)C)[(size_t)(crow0 + reg) * N + ccol] = v;
            }
        }
    }
}

// ---------------- V transpose to global: Vt_g[bn][d][key] ----------------
__global__ __launch_bounds__(256) void vtrans(const unsigned short* __restrict__ whb,
                                              unsigned short* __restrict__ vtg) {
    __shared__ unsigned short tile[64][72];
    const int bn = blockIdx.y;
    const int b = bn >> 4, n = bn & 15, nb = n * 64;
    const int jt0 = blockIdx.x * 64;
    const int tid = threadIdx.x;
#pragma unroll
    for (int g = 0; g < 2; ++g) {
        int f = g * 256 + tid;
        int key = f >> 3, c = f & 7;
        uint4v v = *(const uint4v*)&whb[((size_t)(jt0 + key) * 4 + b) * 3072 + 2048 + nb + c * 8];
        *(uint4v*)&tile[key][c * 8] = v;
    }
    __syncthreads();
#pragma unroll
    for (int g = 0; g < 2; ++g) {
        int f = g * 256 + tid;
        int d = f >> 3, ck = f & 7;
        unsigned short tmp[8];
#pragma unroll
        for (int e = 0; e < 8; ++e) tmp[e] = tile[ck * 8 + e][d];
        *(uint4v*)&vtg[(size_t)bn * 131072 + (size_t)d * 2048 + jt0 + ck * 8] = *(uint4v*)tmp;
    }
}

// ---------------- MFMA flash attention: split-K balanced; exp2-domain softmax --------
// Q prescale folds 0.125*log2(e); all exps are raw v_exp (exp2f). Merge also exp2.
__global__ __launch_bounds__(512) void flash_attn_mfma(const unsigned short* __restrict__ whb,
                                                       const unsigned short* __restrict__ rhkb,
                                                       const unsigned short* __restrict__ vtg,
                                                       const float* __restrict__ r_w_bias,
                                                       const float* __restrict__ r_r_bias,
                                                       float* __restrict__ opart,
                                                       float* __restrict__ ml) {
    const int bid = blockIdx.x;
    const int bn = bid >> 3;
    const int kk0 = bid & 7;
    const int b = bn >> 4, n = bn & 15, nb = n * 64;
    const int tid = threadIdx.x;
    const int wq = tid >> 6;
    const int lane = tid & 63;
    const int rg = lane >> 4;
    const int lc = lane & 15;
    const int m7 = lc & 7;
    const float QSCALE = 0.125f * 1.44269504089f;  // 1/sqrt(64) * log2(e)

    __shared__ __align__(16) unsigned short Ks[4096];
    __shared__ __align__(16) unsigned short Rs[16384];
    __shared__ __align__(16) unsigned short Vt[4096];
    __shared__ __align__(16) unsigned short SCR[8][1440];

    const int wbase_off = 112 - 16 * wq;
    const int srow = tid >> 3;
    const int sc = tid & 7;
    unsigned short* scr = &SCR[wq][0];

#pragma unroll 1
    for (int job = 0; job < 2; ++job) {
        const int h = job;
        const int bx = job ? (7 - kk0) : kk0;
        const int i0 = bx << 7;
        const int halfn = bx + 9;
        const int kt0 = h * halfn;
        const int ktend = kt0 + halfn;

        bf16x8 qac0, qac1, qbd0, qbd1;
        {
            const int qrow = MLEN + i0 + wq * 16 + lc;
            const unsigned short* qp = whb + ((size_t)qrow * 4 + b) * 3072 + nb + rg * 8;
            bf16x8 q0 = *(const bf16x8*)(qp);
            bf16x8 q1 = *(const bf16x8*)(qp + 32);
            const float* wbp = r_w_bias + nb + rg * 8;
            const float* rbp = r_r_bias + nb + rg * 8;
#pragma unroll
            for (int e = 0; e < 8; ++e) {
                const float v0 = bf2f((unsigned short)q0[e]);
                const float v1 = bf2f((unsigned short)q1[e]);
                qac0[e] = (short)f2bf((v0 + wbp[e]) * QSCALE);
                qbd0[e] = (short)f2bf((v0 + rbp[e]) * QSCALE);
                qac1[e] = (short)f2bf((v1 + wbp[32 + e]) * QSCALE);
                qbd1[e] = (short)f2bf((v1 + rbp[32 + e]) * QSCALE);
            }
        }

        f32x4 Oacc[4] = {};
        float mrun = -INFINITY, lrun = 0.f;

        uint4v pk, pv, pr3[3];
        {
            const int j0 = kt0 << 6;
            pk = *(const uint4v*)&whb[((size_t)(j0 + srow) * 4 + b) * 3072 + 1024 + nb + sc * 8];
            pv = *(const uint4v*)&vtg[(size_t)bn * 131072 + (size_t)srow * 2048 + j0 + sc * 8];
            const int relst = j0 - i0 + 896;
#pragma unroll
            for (int p = 0; p < 3; ++p) {
                int a = relst + p * 64 + srow;
                if (a > 2047) a = 2047;
                pr3[p] = *(const uint4v*)&rhkb[(size_t)a * 1024 + nb + sc * 8];
            }
        }

        for (int kt = kt0; kt < ktend; ++kt) {
            const int jt0 = kt << 6;
            const int relbase = jt0 - i0 + 896;
            __syncthreads();

            *(uint4v*)&Ks[srow * 64 + ((sc ^ (srow & 7)) << 3)] = pk;
            *(uint4v*)&Vt[srow * 64 + ((sc ^ (srow & 7)) << 3)] = pv;
            if (kt == kt0) {
#pragma unroll
                for (int p = 0; p < 3; ++p) {
                    int a = relbase + p * 64 + srow;
                    if (a > 2047) a = 2047;
                    const int dst = ((a >> 6) & 3) * 4096 + (a & 63) * 64 + ((sc ^ (a & 7)) << 3);
                    *(uint4v*)&Rs[dst] = pr3[p];
                }
            } else {
                int a = relbase + 128 + srow;
                if (a > 2047) a = 2047;
                const int dst = ((a >> 6) & 3) * 4096 + (a & 63) * 64 + ((sc ^ (a & 7)) << 3);
                *(uint4v*)&Rs[dst] = pr3[0];
            }
            if (kt + 1 < ktend) {
                const int jn = jt0 + 64;
                pk = *(const uint4v*)&whb[((size_t)(jn + srow) * 4 + b) * 3072 + 1024 + nb + sc * 8];
                pv = *(const uint4v*)&vtg[(size_t)bn * 131072 + (size_t)srow * 2048 + jn + sc * 8];
                int a = relbase + 192 + srow;
                if (a > 2047) a = 2047;
                pr3[0] = *(const uint4v*)&rhkb[(size_t)a * 1024 + nb + sc * 8];
            }
            __syncthreads();

            // ---- AC^T ----
            f32x4 S[4];
            __builtin_amdgcn_s_setprio(1);
#pragma unroll
            for (int nf = 0; nf < 4; ++nf) {
                const int row = nf * 16 + lc;
                const bf16x8 kf0 = *(const bf16x8*)&Ks[row * 64 + ((rg ^ m7) << 3)];
                const bf16x8 kf1 = *(const bf16x8*)&Ks[row * 64 + (((4 + rg) ^ m7) << 3)];
                f32x4 zz = {0.f, 0.f, 0.f, 0.f};
                zz = __builtin_amdgcn_mfma_f32_16x16x32_bf16(kf0, qac0, zz, 0, 0, 0);
                S[nf] = __builtin_amdgcn_mfma_f32_16x16x32_bf16(kf1, qac1, zz, 0, 0, 0);
            }
            __builtin_amdgcn_s_setprio(0);

            // ---- BD^T band -> [w][q] pitch 18 ----
            const int wbase = relbase + wbase_off;
#pragma unroll
            for (int g = 0; g < 5; ++g) {
                const int a = wbase + g * 16 + lc;
                const int rbase = ((a >> 6) & 3) * 4096 + (a & 63) * 64;
                const bf16x8 rf0 = *(const bf16x8*)&Rs[rbase + ((rg ^ m7) << 3)];
                const bf16x8 rf1 = *(const bf16x8*)&Rs[rbase + (((4 + rg) ^ m7) << 3)];
                f32x4 bd = {0.f, 0.f, 0.f, 0.f};
                bd = __builtin_amdgcn_mfma_f32_16x16x32_bf16(rf0, qbd0, bd, 0, 0, 0);
                bd = __builtin_amdgcn_mfma_f32_16x16x32_bf16(rf1, qbd1, bd, 0, 0, 0);
                const int wrow = g * 16 + rg * 4;
#pragma unroll
                for (int r = 0; r < 4; ++r)
                    scr[(wrow + r) * 18 + lc] = f2bf(bd[r]);
            }

            // ---- scores ----
            const bool needmask = (wbase + 78 > 2047);
            float tmax = -INFINITY;
#pragma unroll
            for (int nf = 0; nf < 4; ++nf) {
#pragma unroll
                for (int r = 0; r < 4; ++r) {
                    const int wb_ = 15 + nf * 16 + rg * 4 + r - lc;
                    float s = S[nf][r] + bf2f(scr[wb_ * 18 + lc]);
                    if (needmask) s = (wbase + wb_ <= 2047) ? s : -INFINITY;
                    S[nf][r] = s;
                    tmax = fmaxf(tmax, s);
                }
            }

            // ---- online softmax (exp2 domain) ----
            tmax = fmaxf(tmax, __shfl_xor(tmax, 16));
            tmax = fmaxf(tmax, __shfl_xor(tmax, 32));
            const float mn = fmaxf(mrun, tmax);
            const float ef = exp2f(mrun - mn);
            mrun = mn;
            float rsum = 0.f;
#pragma unroll
            for (int nf = 0; nf < 4; ++nf) {
#pragma unroll
                for (int r = 0; r < 4; ++r) {
                    const float p = exp2f(S[nf][r] - mn);
                    S[nf][r] = p;
                    rsum += p;
                }
            }
            rsum += __shfl_xor(rsum, 16);
            rsum += __shfl_xor(rsum, 32);
            lrun = lrun * ef + rsum;
            if (__any(ef < 1.0f)) {
#pragma unroll
                for (int nf = 0; nf < 4; ++nf)
#pragma unroll
                    for (int r = 0; r < 4; ++r) Oacc[nf][r] *= ef;
            }

            // ---- stage P [q][64] chunk-XOR ----
#pragma unroll
            for (int nf = 0; nf < 4; ++nf) {
                ushort4 pw = {f2bf(S[nf][0]), f2bf(S[nf][1]), f2bf(S[nf][2]), f2bf(S[nf][3])};
                const int chunk = nf * 2 + (rg >> 1);
                *(ushort4*)&scr[lc * 64 + ((chunk ^ m7) << 3) + ((rg & 1) << 2)] = pw;
            }

            // ---- PV ----
            {
                const bf16x8 pf0 = *(const bf16x8*)&scr[lc * 64 + ((rg ^ m7) << 3)];
                const bf16x8 pf1 = *(const bf16x8*)&scr[lc * 64 + (((4 + rg) ^ m7) << 3)];
                __builtin_amdgcn_s_setprio(1);
#pragma unroll
                for (int nf = 0; nf < 4; ++nf) {
                    const int row = nf * 16 + lc;
                    const bf16x8 vf0 = *(const bf16x8*)&Vt[row * 64 + ((rg ^ m7) << 3)];
                    const bf16x8 vf1 = *(const bf16x8*)&Vt[row * 64 + (((4 + rg) ^ m7) << 3)];
                    Oacc[nf] = __builtin_amdgcn_mfma_f32_16x16x32_bf16(vf0, pf0, Oacc[nf], 0, 0, 0);
                    Oacc[nf] = __builtin_amdgcn_mfma_f32_16x16x32_bf16(vf1, pf1, Oacc[nf], 0, 0, 0);
                }
                __builtin_amdgcn_s_setprio(0);
            }
        }

        // ---- write unnormalized partials ----
        const int qg = i0 + wq * 16 + lc;
        const int rowf = qg * 4 + b;
        float* op = opart + (size_t)h * 4194304 + (size_t)rowf * 1024 + nb;
#pragma unroll
        for (int nf = 0; nf < 4; ++nf) {
            float4 o = {Oacc[nf][0], Oacc[nf][1], Oacc[nf][2], Oacc[nf][3]};
            *(float4*)&op[nf * 16 + rg * 4] = o;
        }
        if (rg == 0) {
            float* mp = ml + (size_t)h * 131072 + ((size_t)rowf * 16 + n) * 2;
            mp[0] = mrun;
            mp[1] = lrun;
        }
    }
}

// ---------------- merge the two split-K halves (exp2 domain) ----------------
__global__ __launch_bounds__(256) void merge_attn(const float* __restrict__ opart,
                                                  const float* __restrict__ ml,
                                                  unsigned short* __restrict__ avb) {
    const size_t g = (size_t)blockIdx.x * 256 + threadIdx.x;
    const size_t c4 = g << 2;
    const int row = (int)(c4 >> 10);
    const int col = (int)(c4 & 1023);
    const int n = col >> 6;
    const size_t mlb = ((size_t)row * 16 + n) * 2;
    const float m1 = ml[mlb], l1 = ml[mlb + 1];
    const float m2 = ml[131072 + mlb], l2 = ml[131072 + mlb + 1];
    const float m = fmaxf(m1, m2);
    const float e1 = exp2f(m1 - m), e2 = exp2f(m2 - m);
    const float inv = 1.0f / (e1 * l1 + e2 * l2);
    const float s1 = e1 * inv, s2 = e2 * inv;
    const float4 o1 = *(const float4*)&opart[c4];
    const float4 o2 = *(const float4*)&opart[4194304 + c4];
    ushort4 o = {f2bf(o1.x * s1 + o2.x * s2), f2bf(o1.y * s1 + o2.y * s2),
                 f2bf(o1.z * s1 + o2.z * s2), f2bf(o1.w * s1 + o2.w * s2)};
    *(ushort4*)&avb[c4] = o;
}

// ---------------- residual add + layernorm (b-branch bf16, vectorized) ----------------
__global__ __launch_bounds__(256) void add_ln_kernel(const float* __restrict__ a,
                                                     const unsigned short* __restrict__ b,
                                                     const float* __restrict__ w,
                                                     const float* __restrict__ bias,
                                                     float* __restrict__ out,
                                                     unsigned short* __restrict__ out_bf) {
    const int row = blockIdx.x;
    const int t = threadIdx.x;
    const int c0 = t << 2;
    __shared__ float red[256];

    const float4 av = *(const float4*)&a[(size_t)row * DM + c0];
    const ushort4 bu = *(const ushort4*)&b[(size_t)row * DM + c0];
    float x0 = av.x + bf2f(bu.x), x1 = av.y + bf2f(bu.y);
    float x2 = av.z + bf2f(bu.z), x3 = av.w + bf2f(bu.w);

    red[t] = x0 + x1 + x2 + x3;
    __syncthreads();
    for (int off = 128; off > 0; off >>= 1) {
        if (t < off) red[t] += red[t + off];
        __syncthreads();
    }
    const float mu = red[0] * (1.0f / DM);
    __syncthreads();

    const float d0 = x0 - mu, d1 = x1 - mu, d2 = x2 - mu, d3 = x3 - mu;
    red[t] = d0 * d0 + d1 * d1 + d2 * d2 + d3 * d3;
    __syncthreads();
    for (int off = 128; off > 0; off >>= 1) {
        if (t < off) red[t] += red[t + off];
        __syncthreads();
    }
    const float rstd = rsqrtf(red[0] * (1.0f / DM) + LN_EPS);

    const float4 wv = *(const float4*)&w[c0];
    const float4 bsv = *(const float4*)&bias[c0];
    float4 o = {d0 * rstd * wv.x + bsv.x, d1 * rstd * wv.y + bsv.y,
                d2 * rstd * wv.z + bsv.z, d3 * rstd * wv.w + bsv.w};
    *(float4*)&out[(size_t)row * DM + c0] = o;
    if (out_bf) {
        ushort4 ob = {f2bf(o.x), f2bf(o.y), f2bf(o.z), f2bf(o.w)};
        *(ushort4*)&out_bf[(size_t)row * DM + c0] = ob;
    }
}

extern "C" void kernel_launch(void* const* d_in, const int* in_sizes, int n_in,
                              void* d_out, int out_size, void* d_ws, size_t ws_size,
                              hipStream_t stream) {
    const float* dec_inp  = (const float*)d_in[0];
    const float* r        = (const float*)d_in[1];
    const float* r_w_bias = (const float*)d_in[2];
    const float* r_r_bias = (const float*)d_in[3];
    const float* mems     = (const float*)d_in[4];
    const float* qkv_w    = (const float*)d_in[6];
    const float* r_w      = (const float*)d_in[7];
    const float* o_w      = (const float*)d_in[8];
    const float* ln1_w    = (const float*)d_in[9];
    const float* ln1_b    = (const float*)d_in[10];
    const float* ln2_w    = (const float*)d_in[11];
    const float* ln2_b    = (const float*)d_in[12];
    const float* ff_w1    = (const float*)d_in[13];
    const float* ff_b1    = (const float*)d_in[14];
    const float* ff_w2    = (const float*)d_in[15];
    const float* ff_b2    = (const float*)d_in[16];
    float* out = (float*)d_out;
    char* ws = (char*)d_ws;

    unsigned short* catb  = (unsigned short*)(ws + OFF_CATB);
    unsigned short* vtg   = (unsigned short*)(ws + OFF_VTG);
    unsigned short* whb   = (unsigned short*)(ws + OFF_WHB);
    unsigned short* rb    = (unsigned short*)(ws + OFF_RB);
    unsigned short* rhkb  = (unsigned short*)(ws + OFF_RHKB);
    unsigned short* avb   = (unsigned short*)(ws + OFF_AVB);
    unsigned short* tmpb  = (unsigned short*)(ws + OFF_TMPB);
    float*          mlbuf = (float*)(ws + OFF_ML);
    float*          ln1f  = (float*)(ws + OFF_LN1F);
    unsigned short* ln1b  = (unsigned short*)(ws + OFF_LN1B);
    unsigned short* ffhb  = (unsigned short*)(ws + OFF_FFHB);
    float*          opart = (float*)(ws + OFF_FFHB);
    unsigned short* qkvwT = (unsigned short*)(ws + OFF_QKVWT);
    unsigned short* rwT   = (unsigned short*)(ws + OFF_RWT);
    unsigned short* owT   = (unsigned short*)(ws + OFF_OWT);
    unsigned short* ffw1T = (unsigned short*)(ws + OFF_FFW1T);
    unsigned short* ffw2T = (unsigned short*)(ws + OFF_FFW2T);

    // casts & fused weight transposes
    cast_cat<<<dim3(4096), 256, 0, stream>>>(mems, dec_inp, catb);
    cast_f32_bf16<<<dim3(1024), 256, 0, stream>>>(r, rb);
    transpose_cast_all<<<dim3(13312), 256, 0, stream>>>(
        qkv_w, r_w, o_w, ff_w1, ff_w2, qkvwT, rwT, owT, ffw1T, ffw2T);

    // projections (wide tile for the big ones)
    gemm_bf16_wide<<<dim3(24, 32), 512, 0, stream>>>(catb, qkvwT, nullptr, whb,
                                                     KLEN * BSZ, 3 * NHD, DM, 4);
    gemm_bf16<<<dim3(8, 16), 256, 0, stream>>>(rb, rwT, nullptr, rhkb,
                                               KLEN, NHD, DM, 4);

    // attention precompute
    vtrans<<<dim3(32, 64), 256, 0, stream>>>(whb, vtg);

    // split-K flash attention + merge
    flash_attn_mfma<<<dim3(512), 512, 0, stream>>>(
        whb, rhkb, vtg, r_w_bias, r_r_bias, opart, mlbuf);
    merge_attn<<<dim3(4096), 256, 0, stream>>>(opart, mlbuf, avb);

    // output projection (bf16 out) + LN + FFN + LN
    gemm_bf16<<<dim3(8, 32), 256, 0, stream>>>(avb, owT, nullptr, tmpb,
                                               QLEN * BSZ, DM, NHD, 4);
    add_ln_kernel<<<dim3(QLEN * BSZ), 256, 0, stream>>>(
        dec_inp, tmpb, ln1_w, ln1_b, ln1f, ln1b);
    gemm_bf16_wide<<<dim3(32, 16), 512, 0, stream>>>(ln1b, ffw1T, ff_b1, ffhb,
                                                     QLEN * BSZ, DI, DM, 1 | 2 | 4);
    gemm_bf16<<<dim3(8, 32), 256, 0, stream>>>(ffhb, ffw2T, ff_b2, tmpb,
                                               QLEN * BSZ, DM, DI, 1 | 4);
    add_ln_kernel<<<dim3(QLEN * BSZ), 256, 0, stream>>>(
        ln1f, tmpb, ln2_w, ln2_b, out, nullptr);
}

// Round 18
// 369.995 us; speedup vs baseline: 1.1708x; 1.1708x over previous
//
#include <hip/hip_runtime.h>
#include <hip/hip_bf16.h>
#include <math.h>

#define QLEN 1024
#define MLEN 1024
#define BSZ 4
#define KLEN 2048
#define NH 16
#define DH 64
#define DM 1024
#define DI 4096
#define NHD 1024
#define LN_EPS 1e-5f

typedef short bf16x8 __attribute__((ext_vector_type(8)));
typedef float f32x4 __attribute__((ext_vector_type(4)));
typedef unsigned int uint4v __attribute__((ext_vector_type(4)));

__device__ __forceinline__ float bf2f(unsigned short u) {
    union { unsigned u32; float f; } x; x.u32 = ((unsigned)u) << 16; return x.f;
}
__device__ __forceinline__ unsigned short f2bf(float f) {
    __hip_bfloat16 h = __float2bfloat16(f);
    return *(unsigned short*)&h;
}

// ---------------- workspace layout (BYTE offsets) ----------------
static const size_t OFF_CATB  = 0;
static const size_t OFF_VTG   = 0;
static const size_t OFF_WHB   = 16777216;
static const size_t OFF_RB    = 67108864;
static const size_t OFF_RHKB  = 71303168;
static const size_t OFF_AVB   = 75497472;
static const size_t OFF_TMPB  = 83886080;
static const size_t OFF_ML    = 92274688;
static const size_t OFF_LN1F  = 100663296;
static const size_t OFF_LN1B  = 117440512;
static const size_t OFF_FFHB  = 125829120;
static const size_t OFF_QKVWT = 159383552;
static const size_t OFF_RWT   = 165675008;
static const size_t OFF_OWT   = 167772160;
static const size_t OFF_FFW1T = 169869312;
static const size_t OFF_FFW2T = 178257920;

// ---------------- casts ----------------
__global__ __launch_bounds__(256) void cast_cat(const float* __restrict__ mems,
                                                const float* __restrict__ dec,
                                                unsigned short* __restrict__ out) {
    size_t i8 = ((size_t)blockIdx.x * 256 + threadIdx.x) * 8;
    const size_t half = (size_t)MLEN * BSZ * DM;
    const float* src = (i8 < half) ? (mems + i8) : (dec + (i8 - half));
    float4 v0 = *(const float4*)src;
    float4 v1 = *(const float4*)(src + 4);
    ushort4 o0 = {f2bf(v0.x), f2bf(v0.y), f2bf(v0.z), f2bf(v0.w)};
    ushort4 o1 = {f2bf(v1.x), f2bf(v1.y), f2bf(v1.z), f2bf(v1.w)};
    *(ushort4*)&out[i8] = o0;
    *(ushort4*)&out[i8 + 4] = o1;
}

__global__ __launch_bounds__(256) void cast_f32_bf16(const float* __restrict__ in,
                                                     unsigned short* __restrict__ out) {
    size_t i8 = ((size_t)blockIdx.x * 256 + threadIdx.x) * 8;
    float4 v0 = *(const float4*)(in + i8);
    float4 v1 = *(const float4*)(in + i8 + 4);
    ushort4 o0 = {f2bf(v0.x), f2bf(v0.y), f2bf(v0.z), f2bf(v0.w)};
    ushort4 o1 = {f2bf(v1.x), f2bf(v1.y), f2bf(v1.z), f2bf(v1.w)};
    *(ushort4*)&out[i8] = o0;
    *(ushort4*)&out[i8 + 4] = o1;
}

// all 5 weight transposes fused: [K][N] fp32 -> [N][K] bf16
__global__ __launch_bounds__(256) void transpose_cast_all(
        const float* __restrict__ qkv_w, const float* __restrict__ r_w,
        const float* __restrict__ o_w,  const float* __restrict__ ff_w1,
        const float* __restrict__ ff_w2,
        unsigned short* __restrict__ qkvwT, unsigned short* __restrict__ rwT,
        unsigned short* __restrict__ owT, unsigned short* __restrict__ ffw1T,
        unsigned short* __restrict__ ffw2T) {
    __shared__ float tile[32][33];
    const int bid = blockIdx.x;
    const float* in; unsigned short* out; int K, N, nx, lid;
    if (bid < 3072)      { in = qkv_w; out = qkvwT; K = 1024; N = 3072; nx = 96;  lid = bid; }
    else if (bid < 4096) { in = r_w;   out = rwT;   K = 1024; N = 1024; nx = 32;  lid = bid - 3072; }
    else if (bid < 5120) { in = o_w;   out = owT;   K = 1024; N = 1024; nx = 32;  lid = bid - 4096; }
    else if (bid < 9216) { in = ff_w1; out = ffw1T; K = 1024; N = 4096; nx = 128; lid = bid - 5120; }
    else                 { in = ff_w2; out = ffw2T; K = 4096; N = 1024; nx = 32;  lid = bid - 9216; }
    const int n0 = (lid % nx) * 32;
    const int k0 = (lid / nx) * 32;
    const int t = threadIdx.x;
    const int r = t >> 3;
    const int c0 = (t & 7) << 2;
    float4 v = *(const float4*)&in[(size_t)(k0 + r) * N + n0 + c0];
    tile[r][c0 + 0] = v.x; tile[r][c0 + 1] = v.y;
    tile[r][c0 + 2] = v.z; tile[r][c0 + 3] = v.w;
    __syncthreads();
    ushort4 o = {f2bf(tile[c0 + 0][r]), f2bf(tile[c0 + 1][r]),
                 f2bf(tile[c0 + 2][r]), f2bf(tile[c0 + 3][r])};
    *(ushort4*)&out[(size_t)(n0 + r) * K + k0 + c0] = o;
}

// ---------------- bf16 MFMA GEMM 128x128 (proven: reg-staged dbuf + XOR swizzle) ------
__global__ __launch_bounds__(256) void gemm_bf16(const unsigned short* __restrict__ A,
                                                 const unsigned short* __restrict__ Bt,
                                                 const float* __restrict__ bias,
                                                 void* __restrict__ C,
                                                 int M, int N, int K, int flags) {
    __shared__ __align__(16) unsigned short As[128 * 64];
    __shared__ __align__(16) unsigned short Bs[128 * 64];

    const int tid = threadIdx.x;
    const int w = tid >> 6, l = tid & 63;
    const int wr = w >> 1, wc = w & 1;
    const int row0 = blockIdx.y * 128;
    const int col0 = blockIdx.x * 128;

    f32x4 acc[4][4] = {};

    uint4v ra[4], rb[4];
    {
#pragma unroll
        for (int q = 0; q < 4; ++q) {
            int f = q * 256 + tid, r = f >> 3, c = f & 7;
            ra[q] = *(const uint4v*)&A[(size_t)(row0 + r) * K + c * 8];
            rb[q] = *(const uint4v*)&Bt[(size_t)(col0 + r) * K + c * 8];
        }
    }

    const int nt = K >> 6;
    for (int kt = 0; kt < nt; ++kt) {
        __syncthreads();
#pragma unroll
        for (int q = 0; q < 4; ++q) {
            int f = q * 256 + tid, r = f >> 3, c = f & 7;
            int sw = (c ^ (r & 7)) << 3;
            *(uint4v*)&As[r * 64 + sw] = ra[q];
            *(uint4v*)&Bs[r * 64 + sw] = rb[q];
        }
        __syncthreads();
        if (kt + 1 < nt) {
            const int k0 = (kt + 1) << 6;
#pragma unroll
            for (int q = 0; q < 4; ++q) {
                int f = q * 256 + tid, r = f >> 3, c = f & 7;
                ra[q] = *(const uint4v*)&A[(size_t)(row0 + r) * K + k0 + c * 8];
                rb[q] = *(const uint4v*)&Bt[(size_t)(col0 + r) * K + k0 + c * 8];
            }
        }
#pragma unroll
        for (int ks = 0; ks < 2; ++ks) {
            bf16x8 a[4], bfr[4];
#pragma unroll
            for (int m = 0; m < 4; ++m) {
                int arow = wr * 64 + m * 16 + (l & 15);
                int chunk = (ks * 4 + (l >> 4)) ^ (arow & 7);
                a[m] = *(const bf16x8*)&As[arow * 64 + chunk * 8];
            }
#pragma unroll
            for (int n = 0; n < 4; ++n) {
                int brow = wc * 64 + n * 16 + (l & 15);
                int chunk = (ks * 4 + (l >> 4)) ^ (brow & 7);
                bfr[n] = *(const bf16x8*)&Bs[brow * 64 + chunk * 8];
            }
#pragma unroll
            for (int m = 0; m < 4; ++m)
#pragma unroll
                for (int n = 0; n < 4; ++n)
                    acc[m][n] = __builtin_amdgcn_mfma_f32_16x16x32_bf16(a[m], bfr[n], acc[m][n], 0, 0, 0);
        }
    }

#pragma unroll
    for (int n = 0; n < 4; ++n) {
        const int ccol = col0 + wc * 64 + n * 16 + (l & 15);
        const float bv = (flags & 1) ? bias[ccol] : 0.0f;
#pragma unroll
        for (int m = 0; m < 4; ++m) {
            const int crow0 = row0 + wr * 64 + m * 16 + ((l >> 4) << 2);
#pragma unroll
            for (int reg = 0; reg < 4; ++reg) {
                float v = acc[m][n][reg] + bv;
                if (flags & 2) v = fmaxf(v, 0.0f);
                if (flags & 4)
                    ((unsigned short*)C)[(size_t)(crow0 + reg) * N + ccol] = f2bf(v);
                else
                    ((float*)C)[(size_t)(crow0 + reg) * N + ccol] = v;
            }
        }
    }
}

// ---------------- V transpose to global: Vt_g[bn][d][key] ----------------
__global__ __launch_bounds__(256) void vtrans(const unsigned short* __restrict__ whb,
                                              unsigned short* __restrict__ vtg) {
    __shared__ unsigned short tile[64][72];
    const int bn = blockIdx.y;
    const int b = bn >> 4, n = bn & 15, nb = n * 64;
    const int jt0 = blockIdx.x * 64;
    const int tid = threadIdx.x;
#pragma unroll
    for (int g = 0; g < 2; ++g) {
        int f = g * 256 + tid;
        int key = f >> 3, c = f & 7;
        uint4v v = *(const uint4v*)&whb[((size_t)(jt0 + key) * 4 + b) * 3072 + 2048 + nb + c * 8];
        *(uint4v*)&tile[key][c * 8] = v;
    }
    __syncthreads();
#pragma unroll
    for (int g = 0; g < 2; ++g) {
        int f = g * 256 + tid;
        int d = f >> 3, ck = f & 7;
        unsigned short tmp[8];
#pragma unroll
        for (int e = 0; e < 8; ++e) tmp[e] = tile[ck * 8 + e][d];
        *(uint4v*)&vtg[(size_t)bn * 131072 + (size_t)d * 2048 + jt0 + ck * 8] = *(uint4v*)tmp;
    }
}

// ---------------- MFMA flash attention: split-K balanced; exp2 via v_exp -------------
// Q prescale folds 0.125*log2(e); exps are __builtin_amdgcn_exp2f (raw v_exp_f32).
__global__ __launch_bounds__(512) void flash_attn_mfma(const unsigned short* __restrict__ whb,
                                                       const unsigned short* __restrict__ rhkb,
                                                       const unsigned short* __restrict__ vtg,
                                                       const float* __restrict__ r_w_bias,
                                                       const float* __restrict__ r_r_bias,
                                                       float* __restrict__ opart,
                                                       float* __restrict__ ml) {
    const int bid = blockIdx.x;
    const int bn = bid >> 3;
    const int kk0 = bid & 7;
    const int b = bn >> 4, n = bn & 15, nb = n * 64;
    const int tid = threadIdx.x;
    const int wq = tid >> 6;
    const int lane = tid & 63;
    const int rg = lane >> 4;
    const int lc = lane & 15;
    const int m7 = lc & 7;
    const float QSCALE = 0.125f * 1.44269504089f;  // 1/sqrt(64) * log2(e)

    __shared__ __align__(16) unsigned short Ks[4096];
    __shared__ __align__(16) unsigned short Rs[16384];
    __shared__ __align__(16) unsigned short Vt[4096];
    __shared__ __align__(16) unsigned short SCR[8][1440];

    const int wbase_off = 112 - 16 * wq;
    const int srow = tid >> 3;
    const int sc = tid & 7;
    unsigned short* scr = &SCR[wq][0];

#pragma unroll 1
    for (int job = 0; job < 2; ++job) {
        const int h = job;
        const int bx = job ? (7 - kk0) : kk0;
        const int i0 = bx << 7;
        const int halfn = bx + 9;
        const int kt0 = h * halfn;
        const int ktend = kt0 + halfn;

        bf16x8 qac0, qac1, qbd0, qbd1;
        {
            const int qrow = MLEN + i0 + wq * 16 + lc;
            const unsigned short* qp = whb + ((size_t)qrow * 4 + b) * 3072 + nb + rg * 8;
            bf16x8 q0 = *(const bf16x8*)(qp);
            bf16x8 q1 = *(const bf16x8*)(qp + 32);
            const float* wbp = r_w_bias + nb + rg * 8;
            const float* rbp = r_r_bias + nb + rg * 8;
#pragma unroll
            for (int e = 0; e < 8; ++e) {
                const float v0 = bf2f((unsigned short)q0[e]);
                const float v1 = bf2f((unsigned short)q1[e]);
                qac0[e] = (short)f2bf((v0 + wbp[e]) * QSCALE);
                qbd0[e] = (short)f2bf((v0 + rbp[e]) * QSCALE);
                qac1[e] = (short)f2bf((v1 + wbp[32 + e]) * QSCALE);
                qbd1[e] = (short)f2bf((v1 + rbp[32 + e]) * QSCALE);
            }
        }

        f32x4 Oacc[4] = {};
        float mrun = -INFINITY, lrun = 0.f;

        uint4v pk, pv, pr3[3];
        {
            const int j0 = kt0 << 6;
            pk = *(const uint4v*)&whb[((size_t)(j0 + srow) * 4 + b) * 3072 + 1024 + nb + sc * 8];
            pv = *(const uint4v*)&vtg[(size_t)bn * 131072 + (size_t)srow * 2048 + j0 + sc * 8];
            const int relst = j0 - i0 + 896;
#pragma unroll
            for (int p = 0; p < 3; ++p) {
                int a = relst + p * 64 + srow;
                if (a > 2047) a = 2047;
                pr3[p] = *(const uint4v*)&rhkb[(size_t)a * 1024 + nb + sc * 8];
            }
        }

        for (int kt = kt0; kt < ktend; ++kt) {
            const int jt0 = kt << 6;
            const int relbase = jt0 - i0 + 896;
            __syncthreads();

            *(uint4v*)&Ks[srow * 64 + ((sc ^ (srow & 7)) << 3)] = pk;
            *(uint4v*)&Vt[srow * 64 + ((sc ^ (srow & 7)) << 3)] = pv;
            if (kt == kt0) {
#pragma unroll
                for (int p = 0; p < 3; ++p) {
                    int a = relbase + p * 64 + srow;
                    if (a > 2047) a = 2047;
                    const int dst = ((a >> 6) & 3) * 4096 + (a & 63) * 64 + ((sc ^ (a & 7)) << 3);
                    *(uint4v*)&Rs[dst] = pr3[p];
                }
            } else {
                int a = relbase + 128 + srow;
                if (a > 2047) a = 2047;
                const int dst = ((a >> 6) & 3) * 4096 + (a & 63) * 64 + ((sc ^ (a & 7)) << 3);
                *(uint4v*)&Rs[dst] = pr3[0];
            }
            if (kt + 1 < ktend) {
                const int jn = jt0 + 64;
                pk = *(const uint4v*)&whb[((size_t)(jn + srow) * 4 + b) * 3072 + 1024 + nb + sc * 8];
                pv = *(const uint4v*)&vtg[(size_t)bn * 131072 + (size_t)srow * 2048 + jn + sc * 8];
                int a = relbase + 192 + srow;
                if (a > 2047) a = 2047;
                pr3[0] = *(const uint4v*)&rhkb[(size_t)a * 1024 + nb + sc * 8];
            }
            __syncthreads();

            // ---- AC^T ----
            f32x4 S[4];
            __builtin_amdgcn_s_setprio(1);
#pragma unroll
            for (int nf = 0; nf < 4; ++nf) {
                const int row = nf * 16 + lc;
                const bf16x8 kf0 = *(const bf16x8*)&Ks[row * 64 + ((rg ^ m7) << 3)];
                const bf16x8 kf1 = *(const bf16x8*)&Ks[row * 64 + (((4 + rg) ^ m7) << 3)];
                f32x4 zz = {0.f, 0.f, 0.f, 0.f};
                zz = __builtin_amdgcn_mfma_f32_16x16x32_bf16(kf0, qac0, zz, 0, 0, 0);
                S[nf] = __builtin_amdgcn_mfma_f32_16x16x32_bf16(kf1, qac1, zz, 0, 0, 0);
            }
            __builtin_amdgcn_s_setprio(0);

            // ---- BD^T band -> [w][q] pitch 18 ----
            const int wbase = relbase + wbase_off;
#pragma unroll
            for (int g = 0; g < 5; ++g) {
                const int a = wbase + g * 16 + lc;
                const int rbase = ((a >> 6) & 3) * 4096 + (a & 63) * 64;
                const bf16x8 rf0 = *(const bf16x8*)&Rs[rbase + ((rg ^ m7) << 3)];
                const bf16x8 rf1 = *(const bf16x8*)&Rs[rbase + (((4 + rg) ^ m7) << 3)];
                f32x4 bd = {0.f, 0.f, 0.f, 0.f};
                bd = __builtin_amdgcn_mfma_f32_16x16x32_bf16(rf0, qbd0, bd, 0, 0, 0);
                bd = __builtin_amdgcn_mfma_f32_16x16x32_bf16(rf1, qbd1, bd, 0, 0, 0);
                const int wrow = g * 16 + rg * 4;
#pragma unroll
                for (int r = 0; r < 4; ++r)
                    scr[(wrow + r) * 18 + lc] = f2bf(bd[r]);
            }

            // ---- scores ----
            const bool needmask = (wbase + 78 > 2047);
            float tmax = -INFINITY;
#pragma unroll
            for (int nf = 0; nf < 4; ++nf) {
#pragma unroll
                for (int r = 0; r < 4; ++r) {
                    const int wb_ = 15 + nf * 16 + rg * 4 + r - lc;
                    float s = S[nf][r] + bf2f(scr[wb_ * 18 + lc]);
                    if (needmask) s = (wbase + wb_ <= 2047) ? s : -INFINITY;
                    S[nf][r] = s;
                    tmax = fmaxf(tmax, s);
                }
            }

            // ---- online softmax (exp2 domain, raw v_exp) ----
            tmax = fmaxf(tmax, __shfl_xor(tmax, 16));
            tmax = fmaxf(tmax, __shfl_xor(tmax, 32));
            const float mn = fmaxf(mrun, tmax);
            const float ef = __builtin_amdgcn_exp2f(mrun - mn);
            mrun = mn;
            float rsum = 0.f;
#pragma unroll
            for (int nf = 0; nf < 4; ++nf) {
#pragma unroll
                for (int r = 0; r < 4; ++r) {
                    const float p = __builtin_amdgcn_exp2f(S[nf][r] - mn);
                    S[nf][r] = p;
                    rsum += p;
                }
            }
            rsum += __shfl_xor(rsum, 16);
            rsum += __shfl_xor(rsum, 32);
            lrun = lrun * ef + rsum;
            if (__any(ef < 1.0f)) {
#pragma unroll
                for (int nf = 0; nf < 4; ++nf)
#pragma unroll
                    for (int r = 0; r < 4; ++r) Oacc[nf][r] *= ef;
            }

            // ---- stage P [q][64] chunk-XOR ----
#pragma unroll
            for (int nf = 0; nf < 4; ++nf) {
                ushort4 pw = {f2bf(S[nf][0]), f2bf(S[nf][1]), f2bf(S[nf][2]), f2bf(S[nf][3])};
                const int chunk = nf * 2 + (rg >> 1);
                *(ushort4*)&scr[lc * 64 + ((chunk ^ m7) << 3) + ((rg & 1) << 2)] = pw;
            }

            // ---- PV ----
            {
                const bf16x8 pf0 = *(const bf16x8*)&scr[lc * 64 + ((rg ^ m7) << 3)];
                const bf16x8 pf1 = *(const bf16x8*)&scr[lc * 64 + (((4 + rg) ^ m7) << 3)];
                __builtin_amdgcn_s_setprio(1);
#pragma unroll
                for (int nf = 0; nf < 4; ++nf) {
                    const int row = nf * 16 + lc;
                    const bf16x8 vf0 = *(const bf16x8*)&Vt[row * 64 + ((rg ^ m7) << 3)];
                    const bf16x8 vf1 = *(const bf16x8*)&Vt[row * 64 + (((4 + rg) ^ m7) << 3)];
                    Oacc[nf] = __builtin_amdgcn_mfma_f32_16x16x32_bf16(vf0, pf0, Oacc[nf], 0, 0, 0);
                    Oacc[nf] = __builtin_amdgcn_mfma_f32_16x16x32_bf16(vf1, pf1, Oacc[nf], 0, 0, 0);
                }
                __builtin_amdgcn_s_setprio(0);
            }
        }

        // ---- write unnormalized partials ----
        const int qg = i0 + wq * 16 + lc;
        const int rowf = qg * 4 + b;
        float* op = opart + (size_t)h * 4194304 + (size_t)rowf * 1024 + nb;
#pragma unroll
        for (int nf = 0; nf < 4; ++nf) {
            float4 o = {Oacc[nf][0], Oacc[nf][1], Oacc[nf][2], Oacc[nf][3]};
            *(float4*)&op[nf * 16 + rg * 4] = o;
        }
        if (rg == 0) {
            float* mp = ml + (size_t)h * 131072 + ((size_t)rowf * 16 + n) * 2;
            mp[0] = mrun;
            mp[1] = lrun;
        }
    }
}

// ---------------- merge the two split-K halves (exp2 domain) ----------------
__global__ __launch_bounds__(256) void merge_attn(const float* __restrict__ opart,
                                                  const float* __restrict__ ml,
                                                  unsigned short* __restrict__ avb) {
    const size_t g = (size_t)blockIdx.x * 256 + threadIdx.x;
    const size_t c4 = g << 2;
    const int row = (int)(c4 >> 10);
    const int col = (int)(c4 & 1023);
    const int n = col >> 6;
    const size_t mlb = ((size_t)row * 16 + n) * 2;
    const float m1 = ml[mlb], l1 = ml[mlb + 1];
    const float m2 = ml[131072 + mlb], l2 = ml[131072 + mlb + 1];
    const float m = fmaxf(m1, m2);
    const float e1 = __builtin_amdgcn_exp2f(m1 - m), e2 = __builtin_amdgcn_exp2f(m2 - m);
    const float inv = 1.0f / (e1 * l1 + e2 * l2);
    const float s1 = e1 * inv, s2 = e2 * inv;
    const float4 o1 = *(const float4*)&opart[c4];
    const float4 o2 = *(const float4*)&opart[4194304 + c4];
    ushort4 o = {f2bf(o1.x * s1 + o2.x * s2), f2bf(o1.y * s1 + o2.y * s2),
                 f2bf(o1.z * s1 + o2.z * s2), f2bf(o1.w * s1 + o2.w * s2)};
    *(ushort4*)&avb[c4] = o;
}

// ---------------- residual add + layernorm (b-branch bf16, vectorized) ----------------
__global__ __launch_bounds__(256) void add_ln_kernel(const float* __restrict__ a,
                                                     const unsigned short* __restrict__ b,
                                                     const float* __restrict__ w,
                                                     const float* __restrict__ bias,
                                                     float* __restrict__ out,
                                                     unsigned short* __restrict__ out_bf) {
    const int row = blockIdx.x;
    const int t = threadIdx.x;
    const int c0 = t << 2;
    __shared__ float red[256];

    const float4 av = *(const float4*)&a[(size_t)row * DM + c0];
    const ushort4 bu = *(const ushort4*)&b[(size_t)row * DM + c0];
    float x0 = av.x + bf2f(bu.x), x1 = av.y + bf2f(bu.y);
    float x2 = av.z + bf2f(bu.z), x3 = av.w + bf2f(bu.w);

    red[t] = x0 + x1 + x2 + x3;
    __syncthreads();
    for (int off = 128; off > 0; off >>= 1) {
        if (t < off) red[t] += red[t + off];
        __syncthreads();
    }
    const float mu = red[0] * (1.0f / DM);
    __syncthreads();

    const float d0 = x0 - mu, d1 = x1 - mu, d2 = x2 - mu, d3 = x3 - mu;
    red[t] = d0 * d0 + d1 * d1 + d2 * d2 + d3 * d3;
    __syncthreads();
    for (int off = 128; off > 0; off >>= 1) {
        if (t < off) red[t] += red[t + off];
        __syncthreads();
    }
    const float rstd = rsqrtf(red[0] * (1.0f / DM) + LN_EPS);

    const float4 wv = *(const float4*)&w[c0];
    const float4 bsv = *(const float4*)&bias[c0];
    float4 o = {d0 * rstd * wv.x + bsv.x, d1 * rstd * wv.y + bsv.y,
                d2 * rstd * wv.z + bsv.z, d3 * rstd * wv.w + bsv.w};
    *(float4*)&out[(size_t)row * DM + c0] = o;
    if (out_bf) {
        ushort4 ob = {f2bf(o.x), f2bf(o.y), f2bf(o.z), f2bf(o.w)};
        *(ushort4*)&out_bf[(size_t)row * DM + c0] = ob;
    }
}

extern "C" void kernel_launch(void* const* d_in, const int* in_sizes, int n_in,
                              void* d_out, int out_size, void* d_ws, size_t ws_size,
                              hipStream_t stream) {
    const float* dec_inp  = (const float*)d_in[0];
    const float* r        = (const float*)d_in[1];
    const float* r_w_bias = (const float*)d_in[2];
    const float* r_r_bias = (const float*)d_in[3];
    const float* mems     = (const float*)d_in[4];
    const float* qkv_w    = (const float*)d_in[6];
    const float* r_w      = (const float*)d_in[7];
    const float* o_w      = (const float*)d_in[8];
    const float* ln1_w    = (const float*)d_in[9];
    const float* ln1_b    = (const float*)d_in[10];
    const float* ln2_w    = (const float*)d_in[11];
    const float* ln2_b    = (const float*)d_in[12];
    const float* ff_w1    = (const float*)d_in[13];
    const float* ff_b1    = (const float*)d_in[14];
    const float* ff_w2    = (const float*)d_in[15];
    const float* ff_b2    = (const float*)d_in[16];
    float* out = (float*)d_out;
    char* ws = (char*)d_ws;

    unsigned short* catb  = (unsigned short*)(ws + OFF_CATB);
    unsigned short* vtg   = (unsigned short*)(ws + OFF_VTG);
    unsigned short* whb   = (unsigned short*)(ws + OFF_WHB);
    unsigned short* rb    = (unsigned short*)(ws + OFF_RB);
    unsigned short* rhkb  = (unsigned short*)(ws + OFF_RHKB);
    unsigned short* avb   = (unsigned short*)(ws + OFF_AVB);
    unsigned short* tmpb  = (unsigned short*)(ws + OFF_TMPB);
    float*          mlbuf = (float*)(ws + OFF_ML);
    float*          ln1f  = (float*)(ws + OFF_LN1F);
    unsigned short* ln1b  = (unsigned short*)(ws + OFF_LN1B);
    unsigned short* ffhb  = (unsigned short*)(ws + OFF_FFHB);
    float*          opart = (float*)(ws + OFF_FFHB);
    unsigned short* qkvwT = (unsigned short*)(ws + OFF_QKVWT);
    unsigned short* rwT   = (unsigned short*)(ws + OFF_RWT);
    unsigned short* owT   = (unsigned short*)(ws + OFF_OWT);
    unsigned short* ffw1T = (unsigned short*)(ws + OFF_FFW1T);
    unsigned short* ffw2T = (unsigned short*)(ws + OFF_FFW2T);

    // casts & fused weight transposes
    cast_cat<<<dim3(4096), 256, 0, stream>>>(mems, dec_inp, catb);
    cast_f32_bf16<<<dim3(1024), 256, 0, stream>>>(r, rb);
    transpose_cast_all<<<dim3(13312), 256, 0, stream>>>(
        qkv_w, r_w, o_w, ff_w1, ff_w2, qkvwT, rwT, owT, ffw1T, ffw2T);

    // projections
    gemm_bf16<<<dim3(24, 64), 256, 0, stream>>>(catb, qkvwT, nullptr, whb,
                                                KLEN * BSZ, 3 * NHD, DM, 4);
    gemm_bf16<<<dim3(8, 16), 256, 0, stream>>>(rb, rwT, nullptr, rhkb,
                                               KLEN, NHD, DM, 4);

    // attention precompute
    vtrans<<<dim3(32, 64), 256, 0, stream>>>(whb, vtg);

    // split-K flash attention + merge
    flash_attn_mfma<<<dim3(512), 512, 0, stream>>>(
        whb, rhkb, vtg, r_w_bias, r_r_bias, opart, mlbuf);
    merge_attn<<<dim3(4096), 256, 0, stream>>>(opart, mlbuf, avb);

    // output projection (bf16 out) + LN + FFN + LN
    gemm_bf16<<<dim3(8, 32), 256, 0, stream>>>(avb, owT, nullptr, tmpb,
                                               QLEN * BSZ, DM, NHD, 4);
    add_ln_kernel<<<dim3(QLEN * BSZ), 256, 0, stream>>>(
        dec_inp, tmpb, ln1_w, ln1_b, ln1f, ln1b);
    gemm_bf16<<<dim3(32, 32), 256, 0, stream>>>(ln1b, ffw1T, ff_b1, ffhb,
                                                QLEN * BSZ, DI, DM, 1 | 2 | 4);
    gemm_bf16<<<dim3(8, 32), 256, 0, stream>>>(ffhb, ffw2T, ff_b2, tmpb,
                                               QLEN * BSZ, DM, DI, 1 | 4);
    add_ln_kernel<<<dim3(QLEN * BSZ), 256, 0, stream>>>(
        ln1f, tmpb, ln2_w, ln2_b, out, nullptr);
}

// Round 19
// 362.818 us; speedup vs baseline: 1.1940x; 1.0198x over previous
//
#include <hip/hip_runtime.h>
#include <hip/hip_bf16.h>
#include <math.h>

#define QLEN 1024
#define MLEN 1024
#define BSZ 4
#define KLEN 2048
#define NH 16
#define DH 64
#define DM 1024
#define DI 4096
#define NHD 1024
#define LN_EPS 1e-5f

typedef short bf16x8 __attribute__((ext_vector_type(8)));
typedef float f32x4 __attribute__((ext_vector_type(4)));
typedef unsigned int uint4v __attribute__((ext_vector_type(4)));

__device__ __forceinline__ float bf2f(unsigned short u) {
    union { unsigned u32; float f; } x; x.u32 = ((unsigned)u) << 16; return x.f;
}
__device__ __forceinline__ unsigned short f2bf(float f) {
    __hip_bfloat16 h = __float2bfloat16(f);
    return *(unsigned short*)&h;
}

// ---------------- workspace layout (BYTE offsets) ----------------
static const size_t OFF_CATB  = 0;
static const size_t OFF_VTG   = 0;
static const size_t OFF_WHB   = 16777216;
static const size_t OFF_RB    = 67108864;
static const size_t OFF_RHKB  = 71303168;
static const size_t OFF_AVB   = 75497472;
static const size_t OFF_TMPB  = 83886080;
static const size_t OFF_ML    = 92274688;
static const size_t OFF_LN1B  = 117440512;
static const size_t OFF_FFHB  = 125829120;
static const size_t OFF_QKVWT = 159383552;
static const size_t OFF_RWT   = 165675008;
static const size_t OFF_OWT   = 167772160;
static const size_t OFF_FFW1T = 169869312;
static const size_t OFF_FFW2T = 178257920;

// ---------------- casts ----------------
__global__ __launch_bounds__(256) void cast_cat(const float* __restrict__ mems,
                                                const float* __restrict__ dec,
                                                unsigned short* __restrict__ out) {
    size_t i8 = ((size_t)blockIdx.x * 256 + threadIdx.x) * 8;
    const size_t half = (size_t)MLEN * BSZ * DM;
    const float* src = (i8 < half) ? (mems + i8) : (dec + (i8 - half));
    float4 v0 = *(const float4*)src;
    float4 v1 = *(const float4*)(src + 4);
    ushort4 o0 = {f2bf(v0.x), f2bf(v0.y), f2bf(v0.z), f2bf(v0.w)};
    ushort4 o1 = {f2bf(v1.x), f2bf(v1.y), f2bf(v1.z), f2bf(v1.w)};
    *(ushort4*)&out[i8] = o0;
    *(ushort4*)&out[i8 + 4] = o1;
}

__global__ __launch_bounds__(256) void cast_f32_bf16(const float* __restrict__ in,
                                                     unsigned short* __restrict__ out) {
    size_t i8 = ((size_t)blockIdx.x * 256 + threadIdx.x) * 8;
    float4 v0 = *(const float4*)(in + i8);
    float4 v1 = *(const float4*)(in + i8 + 4);
    ushort4 o0 = {f2bf(v0.x), f2bf(v0.y), f2bf(v0.z), f2bf(v0.w)};
    ushort4 o1 = {f2bf(v1.x), f2bf(v1.y), f2bf(v1.z), f2bf(v1.w)};
    *(ushort4*)&out[i8] = o0;
    *(ushort4*)&out[i8 + 4] = o1;
}

// all 5 weight transposes fused: [K][N] fp32 -> [N][K] bf16
__global__ __launch_bounds__(256) void transpose_cast_all(
        const float* __restrict__ qkv_w, const float* __restrict__ r_w,
        const float* __restrict__ o_w,  const float* __restrict__ ff_w1,
        const float* __restrict__ ff_w2,
        unsigned short* __restrict__ qkvwT, unsigned short* __restrict__ rwT,
        unsigned short* __restrict__ owT, unsigned short* __restrict__ ffw1T,
        unsigned short* __restrict__ ffw2T) {
    __shared__ float tile[32][33];
    const int bid = blockIdx.x;
    const float* in; unsigned short* out; int K, N, nx, lid;
    if (bid < 3072)      { in = qkv_w; out = qkvwT; K = 1024; N = 3072; nx = 96;  lid = bid; }
    else if (bid < 4096) { in = r_w;   out = rwT;   K = 1024; N = 1024; nx = 32;  lid = bid - 3072; }
    else if (bid < 5120) { in = o_w;   out = owT;   K = 1024; N = 1024; nx = 32;  lid = bid - 4096; }
    else if (bid < 9216) { in = ff_w1; out = ffw1T; K = 1024; N = 4096; nx = 128; lid = bid - 5120; }
    else                 { in = ff_w2; out = ffw2T; K = 4096; N = 1024; nx = 32;  lid = bid - 9216; }
    const int n0 = (lid % nx) * 32;
    const int k0 = (lid / nx) * 32;
    const int t = threadIdx.x;
    const int r = t >> 3;
    const int c0 = (t & 7) << 2;
    float4 v = *(const float4*)&in[(size_t)(k0 + r) * N + n0 + c0];
    tile[r][c0 + 0] = v.x; tile[r][c0 + 1] = v.y;
    tile[r][c0 + 2] = v.z; tile[r][c0 + 3] = v.w;
    __syncthreads();
    ushort4 o = {f2bf(tile[c0 + 0][r]), f2bf(tile[c0 + 1][r]),
                 f2bf(tile[c0 + 2][r]), f2bf(tile[c0 + 3][r])};
    *(ushort4*)&out[(size_t)(n0 + r) * K + k0 + c0] = o;
}

// ---------------- bf16 MFMA GEMM 128x128 (proven: reg-staged dbuf + XOR swizzle) ------
__global__ __launch_bounds__(256) void gemm_bf16(const unsigned short* __restrict__ A,
                                                 const unsigned short* __restrict__ Bt,
                                                 const float* __restrict__ bias,
                                                 void* __restrict__ C,
                                                 int M, int N, int K, int flags) {
    __shared__ __align__(16) unsigned short As[128 * 64];
    __shared__ __align__(16) unsigned short Bs[128 * 64];

    const int tid = threadIdx.x;
    const int w = tid >> 6, l = tid & 63;
    const int wr = w >> 1, wc = w & 1;
    const int row0 = blockIdx.y * 128;
    const int col0 = blockIdx.x * 128;

    f32x4 acc[4][4] = {};

    uint4v ra[4], rb[4];
    {
#pragma unroll
        for (int q = 0; q < 4; ++q) {
            int f = q * 256 + tid, r = f >> 3, c = f & 7;
            ra[q] = *(const uint4v*)&A[(size_t)(row0 + r) * K + c * 8];
            rb[q] = *(const uint4v*)&Bt[(size_t)(col0 + r) * K + c * 8];
        }
    }

    const int nt = K >> 6;
    for (int kt = 0; kt < nt; ++kt) {
        __syncthreads();
#pragma unroll
        for (int q = 0; q < 4; ++q) {
            int f = q * 256 + tid, r = f >> 3, c = f & 7;
            int sw = (c ^ (r & 7)) << 3;
            *(uint4v*)&As[r * 64 + sw] = ra[q];
            *(uint4v*)&Bs[r * 64 + sw] = rb[q];
        }
        __syncthreads();
        if (kt + 1 < nt) {
            const int k0 = (kt + 1) << 6;
#pragma unroll
            for (int q = 0; q < 4; ++q) {
                int f = q * 256 + tid, r = f >> 3, c = f & 7;
                ra[q] = *(const uint4v*)&A[(size_t)(row0 + r) * K + k0 + c * 8];
                rb[q] = *(const uint4v*)&Bt[(size_t)(col0 + r) * K + k0 + c * 8];
            }
        }
#pragma unroll
        for (int ks = 0; ks < 2; ++ks) {
            bf16x8 a[4], bfr[4];
#pragma unroll
            for (int m = 0; m < 4; ++m) {
                int arow = wr * 64 + m * 16 + (l & 15);
                int chunk = (ks * 4 + (l >> 4)) ^ (arow & 7);
                a[m] = *(const bf16x8*)&As[arow * 64 + chunk * 8];
            }
#pragma unroll
            for (int n = 0; n < 4; ++n) {
                int brow = wc * 64 + n * 16 + (l & 15);
                int chunk = (ks * 4 + (l >> 4)) ^ (brow & 7);
                bfr[n] = *(const bf16x8*)&Bs[brow * 64 + chunk * 8];
            }
#pragma unroll
            for (int m = 0; m < 4; ++m)
#pragma unroll
                for (int n = 0; n < 4; ++n)
                    acc[m][n] = __builtin_amdgcn_mfma_f32_16x16x32_bf16(a[m], bfr[n], acc[m][n], 0, 0, 0);
        }
    }

#pragma unroll
    for (int n = 0; n < 4; ++n) {
        const int ccol = col0 + wc * 64 + n * 16 + (l & 15);
        const float bv = (flags & 1) ? bias[ccol] : 0.0f;
#pragma unroll
        for (int m = 0; m < 4; ++m) {
            const int crow0 = row0 + wr * 64 + m * 16 + ((l >> 4) << 2);
#pragma unroll
            for (int reg = 0; reg < 4; ++reg) {
                float v = acc[m][n][reg] + bv;
                if (flags & 2) v = fmaxf(v, 0.0f);
                if (flags & 4)
                    ((unsigned short*)C)[(size_t)(crow0 + reg) * N + ccol] = f2bf(v);
                else
                    ((float*)C)[(size_t)(crow0 + reg) * N + ccol] = v;
            }
        }
    }
}

// ---------------- V transpose to global: Vt_g[bn][d][key] ----------------
__global__ __launch_bounds__(256) void vtrans(const unsigned short* __restrict__ whb,
                                              unsigned short* __restrict__ vtg) {
    __shared__ unsigned short tile[64][72];
    const int bn = blockIdx.y;
    const int b = bn >> 4, n = bn & 15, nb = n * 64;
    const int jt0 = blockIdx.x * 64;
    const int tid = threadIdx.x;
#pragma unroll
    for (int g = 0; g < 2; ++g) {
        int f = g * 256 + tid;
        int key = f >> 3, c = f & 7;
        uint4v v = *(const uint4v*)&whb[((size_t)(jt0 + key) * 4 + b) * 3072 + 2048 + nb + c * 8];
        *(uint4v*)&tile[key][c * 8] = v;
    }
    __syncthreads();
#pragma unroll
    for (int g = 0; g < 2; ++g) {
        int f = g * 256 + tid;
        int d = f >> 3, ck = f & 7;
        unsigned short tmp[8];
#pragma unroll
        for (int e = 0; e < 8; ++e) tmp[e] = tile[ck * 8 + e][d];
        *(uint4v*)&vtg[(size_t)bn * 131072 + (size_t)d * 2048 + jt0 + ck * 8] = *(uint4v*)tmp;
    }
}

// ---------------- MFMA flash attention: split-K balanced; exp2 via v_exp -------------
__global__ __launch_bounds__(512) void flash_attn_mfma(const unsigned short* __restrict__ whb,
                                                       const unsigned short* __restrict__ rhkb,
                                                       const unsigned short* __restrict__ vtg,
                                                       const float* __restrict__ r_w_bias,
                                                       const float* __restrict__ r_r_bias,
                                                       float* __restrict__ opart,
                                                       float* __restrict__ ml) {
    const int bid = blockIdx.x;
    const int bn = bid >> 3;
    const int kk0 = bid & 7;
    const int b = bn >> 4, n = bn & 15, nb = n * 64;
    const int tid = threadIdx.x;
    const int wq = tid >> 6;
    const int lane = tid & 63;
    const int rg = lane >> 4;
    const int lc = lane & 15;
    const int m7 = lc & 7;
    const float QSCALE = 0.125f * 1.44269504089f;

    __shared__ __align__(16) unsigned short Ks[4096];
    __shared__ __align__(16) unsigned short Rs[16384];
    __shared__ __align__(16) unsigned short Vt[4096];
    __shared__ __align__(16) unsigned short SCR[8][1440];

    const int wbase_off = 112 - 16 * wq;
    const int srow = tid >> 3;
    const int sc = tid & 7;
    unsigned short* scr = &SCR[wq][0];

#pragma unroll 1
    for (int job = 0; job < 2; ++job) {
        const int h = job;
        const int bx = job ? (7 - kk0) : kk0;
        const int i0 = bx << 7;
        const int halfn = bx + 9;
        const int kt0 = h * halfn;
        const int ktend = kt0 + halfn;

        bf16x8 qac0, qac1, qbd0, qbd1;
        {
            const int qrow = MLEN + i0 + wq * 16 + lc;
            const unsigned short* qp = whb + ((size_t)qrow * 4 + b) * 3072 + nb + rg * 8;
            bf16x8 q0 = *(const bf16x8*)(qp);
            bf16x8 q1 = *(const bf16x8*)(qp + 32);
            const float* wbp = r_w_bias + nb + rg * 8;
            const float* rbp = r_r_bias + nb + rg * 8;
#pragma unroll
            for (int e = 0; e < 8; ++e) {
                const float v0 = bf2f((unsigned short)q0[e]);
                const float v1 = bf2f((unsigned short)q1[e]);
                qac0[e] = (short)f2bf((v0 + wbp[e]) * QSCALE);
                qbd0[e] = (short)f2bf((v0 + rbp[e]) * QSCALE);
                qac1[e] = (short)f2bf((v1 + wbp[32 + e]) * QSCALE);
                qbd1[e] = (short)f2bf((v1 + rbp[32 + e]) * QSCALE);
            }
        }

        f32x4 Oacc[4] = {};
        float mrun = -INFINITY, lrun = 0.f;

        uint4v pk, pv, pr3[3];
        {
            const int j0 = kt0 << 6;
            pk = *(const uint4v*)&whb[((size_t)(j0 + srow) * 4 + b) * 3072 + 1024 + nb + sc * 8];
            pv = *(const uint4v*)&vtg[(size_t)bn * 131072 + (size_t)srow * 2048 + j0 + sc * 8];
            const int relst = j0 - i0 + 896;
#pragma unroll
            for (int p = 0; p < 3; ++p) {
                int a = relst + p * 64 + srow;
                if (a > 2047) a = 2047;
                pr3[p] = *(const uint4v*)&rhkb[(size_t)a * 1024 + nb + sc * 8];
            }
        }

        for (int kt = kt0; kt < ktend; ++kt) {
            const int jt0 = kt << 6;
            const int relbase = jt0 - i0 + 896;
            __syncthreads();

            *(uint4v*)&Ks[srow * 64 + ((sc ^ (srow & 7)) << 3)] = pk;
            *(uint4v*)&Vt[srow * 64 + ((sc ^ (srow & 7)) << 3)] = pv;
            if (kt == kt0) {
#pragma unroll
                for (int p = 0; p < 3; ++p) {
                    int a = relbase + p * 64 + srow;
                    if (a > 2047) a = 2047;
                    const int dst = ((a >> 6) & 3) * 4096 + (a & 63) * 64 + ((sc ^ (a & 7)) << 3);
                    *(uint4v*)&Rs[dst] = pr3[p];
                }
            } else {
                int a = relbase + 128 + srow;
                if (a > 2047) a = 2047;
                const int dst = ((a >> 6) & 3) * 4096 + (a & 63) * 64 + ((sc ^ (a & 7)) << 3);
                *(uint4v*)&Rs[dst] = pr3[0];
            }
            if (kt + 1 < ktend) {
                const int jn = jt0 + 64;
                pk = *(const uint4v*)&whb[((size_t)(jn + srow) * 4 + b) * 3072 + 1024 + nb + sc * 8];
                pv = *(const uint4v*)&vtg[(size_t)bn * 131072 + (size_t)srow * 2048 + jn + sc * 8];
                int a = relbase + 192 + srow;
                if (a > 2047) a = 2047;
                pr3[0] = *(const uint4v*)&rhkb[(size_t)a * 1024 + nb + sc * 8];
            }
            __syncthreads();

            // ---- AC^T ----
            f32x4 S[4];
            __builtin_amdgcn_s_setprio(1);
#pragma unroll
            for (int nf = 0; nf < 4; ++nf) {
                const int row = nf * 16 + lc;
                const bf16x8 kf0 = *(const bf16x8*)&Ks[row * 64 + ((rg ^ m7) << 3)];
                const bf16x8 kf1 = *(const bf16x8*)&Ks[row * 64 + (((4 + rg) ^ m7) << 3)];
                f32x4 zz = {0.f, 0.f, 0.f, 0.f};
                zz = __builtin_amdgcn_mfma_f32_16x16x32_bf16(kf0, qac0, zz, 0, 0, 0);
                S[nf] = __builtin_amdgcn_mfma_f32_16x16x32_bf16(kf1, qac1, zz, 0, 0, 0);
            }
            __builtin_amdgcn_s_setprio(0);

            // ---- BD^T band -> [w][q] pitch 18 ----
            const int wbase = relbase + wbase_off;
#pragma unroll
            for (int g = 0; g < 5; ++g) {
                const int a = wbase + g * 16 + lc;
                const int rbase = ((a >> 6) & 3) * 4096 + (a & 63) * 64;
                const bf16x8 rf0 = *(const bf16x8*)&Rs[rbase + ((rg ^ m7) << 3)];
                const bf16x8 rf1 = *(const bf16x8*)&Rs[rbase + (((4 + rg) ^ m7) << 3)];
                f32x4 bd = {0.f, 0.f, 0.f, 0.f};
                bd = __builtin_amdgcn_mfma_f32_16x16x32_bf16(rf0, qbd0, bd, 0, 0, 0);
                bd = __builtin_amdgcn_mfma_f32_16x16x32_bf16(rf1, qbd1, bd, 0, 0, 0);
                const int wrow = g * 16 + rg * 4;
#pragma unroll
                for (int r = 0; r < 4; ++r)
                    scr[(wrow + r) * 18 + lc] = f2bf(bd[r]);
            }

            // ---- scores ----
            const bool needmask = (wbase + 78 > 2047);
            float tmax = -INFINITY;
#pragma unroll
            for (int nf = 0; nf < 4; ++nf) {
#pragma unroll
                for (int r = 0; r < 4; ++r) {
                    const int wb_ = 15 + nf * 16 + rg * 4 + r - lc;
                    float s = S[nf][r] + bf2f(scr[wb_ * 18 + lc]);
                    if (needmask) s = (wbase + wb_ <= 2047) ? s : -INFINITY;
                    S[nf][r] = s;
                    tmax = fmaxf(tmax, s);
                }
            }

            // ---- online softmax (exp2 domain, raw v_exp) ----
            tmax = fmaxf(tmax, __shfl_xor(tmax, 16));
            tmax = fmaxf(tmax, __shfl_xor(tmax, 32));
            const float mn = fmaxf(mrun, tmax);
            const float ef = __builtin_amdgcn_exp2f(mrun - mn);
            mrun = mn;
            float rsum = 0.f;
#pragma unroll
            for (int nf = 0; nf < 4; ++nf) {
#pragma unroll
                for (int r = 0; r < 4; ++r) {
                    const float p = __builtin_amdgcn_exp2f(S[nf][r] - mn);
                    S[nf][r] = p;
                    rsum += p;
                }
            }
            rsum += __shfl_xor(rsum, 16);
            rsum += __shfl_xor(rsum, 32);
            lrun = lrun * ef + rsum;
            if (__any(ef < 1.0f)) {
#pragma unroll
                for (int nf = 0; nf < 4; ++nf)
#pragma unroll
                    for (int r = 0; r < 4; ++r) Oacc[nf][r] *= ef;
            }

            // ---- stage P [q][64] chunk-XOR ----
#pragma unroll
            for (int nf = 0; nf < 4; ++nf) {
                ushort4 pw = {f2bf(S[nf][0]), f2bf(S[nf][1]), f2bf(S[nf][2]), f2bf(S[nf][3])};
                const int chunk = nf * 2 + (rg >> 1);
                *(ushort4*)&scr[lc * 64 + ((chunk ^ m7) << 3) + ((rg & 1) << 2)] = pw;
            }

            // ---- PV ----
            {
                const bf16x8 pf0 = *(const bf16x8*)&scr[lc * 64 + ((rg ^ m7) << 3)];
                const bf16x8 pf1 = *(const bf16x8*)&scr[lc * 64 + (((4 + rg) ^ m7) << 3)];
                __builtin_amdgcn_s_setprio(1);
#pragma unroll
                for (int nf = 0; nf < 4; ++nf) {
                    const int row = nf * 16 + lc;
                    const bf16x8 vf0 = *(const bf16x8*)&Vt[row * 64 + ((rg ^ m7) << 3)];
                    const bf16x8 vf1 = *(const bf16x8*)&Vt[row * 64 + (((4 + rg) ^ m7) << 3)];
                    Oacc[nf] = __builtin_amdgcn_mfma_f32_16x16x32_bf16(vf0, pf0, Oacc[nf], 0, 0, 0);
                    Oacc[nf] = __builtin_amdgcn_mfma_f32_16x16x32_bf16(vf1, pf1, Oacc[nf], 0, 0, 0);
                }
                __builtin_amdgcn_s_setprio(0);
            }
        }

        // ---- write unnormalized partials ----
        const int qg = i0 + wq * 16 + lc;
        const int rowf = qg * 4 + b;
        float* op = opart + (size_t)h * 4194304 + (size_t)rowf * 1024 + nb;
#pragma unroll
        for (int nf = 0; nf < 4; ++nf) {
            float4 o = {Oacc[nf][0], Oacc[nf][1], Oacc[nf][2], Oacc[nf][3]};
            *(float4*)&op[nf * 16 + rg * 4] = o;
        }
        if (rg == 0) {
            float* mp = ml + (size_t)h * 131072 + ((size_t)rowf * 16 + n) * 2;
            mp[0] = mrun;
            mp[1] = lrun;
        }
    }
}

// ---------------- merge the two split-K halves (8-wide, exp2 domain) ----------------
__global__ __launch_bounds__(256) void merge_attn(const float* __restrict__ opart,
                                                  const float* __restrict__ ml,
                                                  unsigned short* __restrict__ avb) {
    const size_t g = (size_t)blockIdx.x * 256 + threadIdx.x;
    const size_t c8 = g << 3;
    const int row = (int)(c8 >> 10);
    const int col = (int)(c8 & 1023);
    const int n = col >> 6;
    const size_t mlb = ((size_t)row * 16 + n) * 2;
    const float m1 = ml[mlb], l1 = ml[mlb + 1];
    const float m2 = ml[131072 + mlb], l2 = ml[131072 + mlb + 1];
    const float m = fmaxf(m1, m2);
    const float e1 = __builtin_amdgcn_exp2f(m1 - m), e2 = __builtin_amdgcn_exp2f(m2 - m);
    const float inv = 1.0f / (e1 * l1 + e2 * l2);
    const float s1 = e1 * inv, s2 = e2 * inv;
    const float4 oa1 = *(const float4*)&opart[c8];
    const float4 ob1 = *(const float4*)&opart[c8 + 4];
    const float4 oa2 = *(const float4*)&opart[4194304 + c8];
    const float4 ob2 = *(const float4*)&opart[4194304 + c8 + 4];
    ushort4 oa = {f2bf(oa1.x * s1 + oa2.x * s2), f2bf(oa1.y * s1 + oa2.y * s2),
                  f2bf(oa1.z * s1 + oa2.z * s2), f2bf(oa1.w * s1 + oa2.w * s2)};
    ushort4 ob = {f2bf(ob1.x * s1 + ob2.x * s2), f2bf(ob1.y * s1 + ob2.y * s2),
                  f2bf(ob1.z * s1 + ob2.z * s2), f2bf(ob1.w * s1 + ob2.w * s2)};
    *(ushort4*)&avb[c8] = oa;
    *(ushort4*)&avb[c8 + 4] = ob;
}

// ---------------- ln1: a fp32 + b bf16 -> bf16 out only ----------------
__global__ __launch_bounds__(256) void add_ln_kernel(const float* __restrict__ a,
                                                     const unsigned short* __restrict__ b,
                                                     const float* __restrict__ w,
                                                     const float* __restrict__ bias,
                                                     unsigned short* __restrict__ out_bf) {
    const int row = blockIdx.x;
    const int t = threadIdx.x;
    const int c0 = t << 2;
    __shared__ float red[256];

    const float4 av = *(const float4*)&a[(size_t)row * DM + c0];
    const ushort4 bu = *(const ushort4*)&b[(size_t)row * DM + c0];
    float x0 = av.x + bf2f(bu.x), x1 = av.y + bf2f(bu.y);
    float x2 = av.z + bf2f(bu.z), x3 = av.w + bf2f(bu.w);

    red[t] = x0 + x1 + x2 + x3;
    __syncthreads();
    for (int off = 128; off > 0; off >>= 1) {
        if (t < off) red[t] += red[t + off];
        __syncthreads();
    }
    const float mu = red[0] * (1.0f / DM);
    __syncthreads();

    const float d0 = x0 - mu, d1 = x1 - mu, d2 = x2 - mu, d3 = x3 - mu;
    red[t] = d0 * d0 + d1 * d1 + d2 * d2 + d3 * d3;
    __syncthreads();
    for (int off = 128; off > 0; off >>= 1) {
        if (t < off) red[t] += red[t + off];
        __syncthreads();
    }
    const float rstd = rsqrtf(red[0] * (1.0f / DM) + LN_EPS);

    const float4 wv = *(const float4*)&w[c0];
    const float4 bsv = *(const float4*)&bias[c0];
    ushort4 ob = {f2bf(d0 * rstd * wv.x + bsv.x), f2bf(d1 * rstd * wv.y + bsv.y),
                  f2bf(d2 * rstd * wv.z + bsv.z), f2bf(d3 * rstd * wv.w + bsv.w)};
    *(ushort4*)&out_bf[(size_t)row * DM + c0] = ob;
}

// ---------------- ln2: a bf16 + b bf16 -> fp32 out ----------------
__global__ __launch_bounds__(256) void add_ln2_kernel(const unsigned short* __restrict__ a,
                                                      const unsigned short* __restrict__ b,
                                                      const float* __restrict__ w,
                                                      const float* __restrict__ bias,
                                                      float* __restrict__ out) {
    const int row = blockIdx.x;
    const int t = threadIdx.x;
    const int c0 = t << 2;
    __shared__ float red[256];

    const ushort4 au = *(const ushort4*)&a[(size_t)row * DM + c0];
    const ushort4 bu = *(const ushort4*)&b[(size_t)row * DM + c0];
    float x0 = bf2f(au.x) + bf2f(bu.x), x1 = bf2f(au.y) + bf2f(bu.y);
    float x2 = bf2f(au.z) + bf2f(bu.z), x3 = bf2f(au.w) + bf2f(bu.w);

    red[t] = x0 + x1 + x2 + x3;
    __syncthreads();
    for (int off = 128; off > 0; off >>= 1) {
        if (t < off) red[t] += red[t + off];
        __syncthreads();
    }
    const float mu = red[0] * (1.0f / DM);
    __syncthreads();

    const float d0 = x0 - mu, d1 = x1 - mu, d2 = x2 - mu, d3 = x3 - mu;
    red[t] = d0 * d0 + d1 * d1 + d2 * d2 + d3 * d3;
    __syncthreads();
    for (int off = 128; off > 0; off >>= 1) {
        if (t < off) red[t] += red[t + off];
        __syncthreads();
    }
    const float rstd = rsqrtf(red[0] * (1.0f / DM) + LN_EPS);

    const float4 wv = *(const float4*)&w[c0];
    const float4 bsv = *(const float4*)&bias[c0];
    float4 o = {d0 * rstd * wv.x + bsv.x, d1 * rstd * wv.y + bsv.y,
                d2 * rstd * wv.z + bsv.z, d3 * rstd * wv.w + bsv.w};
    *(float4*)&out[(size_t)row * DM + c0] = o;
}

extern "C" void kernel_launch(void* const* d_in, const int* in_sizes, int n_in,
                              void* d_out, int out_size, void* d_ws, size_t ws_size,
                              hipStream_t stream) {
    const float* dec_inp  = (const float*)d_in[0];
    const float* r        = (const float*)d_in[1];
    const float* r_w_bias = (const float*)d_in[2];
    const float* r_r_bias = (const float*)d_in[3];
    const float* mems     = (const float*)d_in[4];
    const float* qkv_w    = (const float*)d_in[6];
    const float* r_w      = (const float*)d_in[7];
    const float* o_w      = (const float*)d_in[8];
    const float* ln1_w    = (const float*)d_in[9];
    const float* ln1_b    = (const float*)d_in[10];
    const float* ln2_w    = (const float*)d_in[11];
    const float* ln2_b    = (const float*)d_in[12];
    const float* ff_w1    = (const float*)d_in[13];
    const float* ff_b1    = (const float*)d_in[14];
    const float* ff_w2    = (const float*)d_in[15];
    const float* ff_b2    = (const float*)d_in[16];
    float* out = (float*)d_out;
    char* ws = (char*)d_ws;

    unsigned short* catb  = (unsigned short*)(ws + OFF_CATB);
    unsigned short* vtg   = (unsigned short*)(ws + OFF_VTG);
    unsigned short* whb   = (unsigned short*)(ws + OFF_WHB);
    unsigned short* rb    = (unsigned short*)(ws + OFF_RB);
    unsigned short* rhkb  = (unsigned short*)(ws + OFF_RHKB);
    unsigned short* avb   = (unsigned short*)(ws + OFF_AVB);
    unsigned short* tmpb  = (unsigned short*)(ws + OFF_TMPB);
    float*          mlbuf = (float*)(ws + OFF_ML);
    unsigned short* ln1b  = (unsigned short*)(ws + OFF_LN1B);
    unsigned short* ffhb  = (unsigned short*)(ws + OFF_FFHB);
    float*          opart = (float*)(ws + OFF_FFHB);
    unsigned short* qkvwT = (unsigned short*)(ws + OFF_QKVWT);
    unsigned short* rwT   = (unsigned short*)(ws + OFF_RWT);
    unsigned short* owT   = (unsigned short*)(ws + OFF_OWT);
    unsigned short* ffw1T = (unsigned short*)(ws + OFF_FFW1T);
    unsigned short* ffw2T = (unsigned short*)(ws + OFF_FFW2T);

    // casts & fused weight transposes
    cast_cat<<<dim3(4096), 256, 0, stream>>>(mems, dec_inp, catb);
    cast_f32_bf16<<<dim3(1024), 256, 0, stream>>>(r, rb);
    transpose_cast_all<<<dim3(13312), 256, 0, stream>>>(
        qkv_w, r_w, o_w, ff_w1, ff_w2, qkvwT, rwT, owT, ffw1T, ffw2T);

    // projections
    gemm_bf16<<<dim3(24, 64), 256, 0, stream>>>(catb, qkvwT, nullptr, whb,
                                                KLEN * BSZ, 3 * NHD, DM, 4);
    gemm_bf16<<<dim3(8, 16), 256, 0, stream>>>(rb, rwT, nullptr, rhkb,
                                               KLEN, NHD, DM, 4);

    // attention precompute
    vtrans<<<dim3(32, 64), 256, 0, stream>>>(whb, vtg);

    // split-K flash attention + merge
    flash_attn_mfma<<<dim3(512), 512, 0, stream>>>(
        whb, rhkb, vtg, r_w_bias, r_r_bias, opart, mlbuf);
    merge_attn<<<dim3(2048), 256, 0, stream>>>(opart, mlbuf, avb);

    // output projection (bf16 out) + LN + FFN + LN
    gemm_bf16<<<dim3(8, 32), 256, 0, stream>>>(avb, owT, nullptr, tmpb,
                                               QLEN * BSZ, DM, NHD, 4);
    add_ln_kernel<<<dim3(QLEN * BSZ), 256, 0, stream>>>(
        dec_inp, tmpb, ln1_w, ln1_b, ln1b);
    gemm_bf16<<<dim3(32, 32), 256, 0, stream>>>(ln1b, ffw1T, ff_b1, ffhb,
                                                QLEN * BSZ, DI, DM, 1 | 2 | 4);
    gemm_bf16<<<dim3(8, 32), 256, 0, stream>>>(ffhb, ffw2T, ff_b2, tmpb,
                                               QLEN * BSZ, DM, DI, 1 | 4);
    add_ln2_kernel<<<dim3(QLEN * BSZ), 256, 0, stream>>>(
        ln1b, tmpb, ln2_w, ln2_b, out);
}